// Round 1
// baseline (669.265 us; speedup 1.0000x reference)
//
#include <hip/hip_runtime.h>
#include <hip/hip_bf16.h>

typedef __attribute__((ext_vector_type(4))) float f32x4;
typedef __attribute__((ext_vector_type(8))) short short8;
typedef __attribute__((ext_vector_type(4))) short short4_t;

#define NWIN 4096
#define LTOK 64
#define CDIM 256

static __device__ __forceinline__ short f2bf(float f) {
    __hip_bfloat16 h = __float2bfloat16(f);
    union { __hip_bfloat16 b; short s; } u; u.b = h;
    return u.s;
}

// ---------------- prep kernels ----------------

__global__ void prep_weights(const float* __restrict__ qw, const float* __restrict__ pw,
                             short* __restrict__ wq, short* __restrict__ wp) {
    int i = blockIdx.x * 256 + threadIdx.x;     // grid 768*256 = 196608
    if (i < 768 * 256) wq[i] = f2bf(qw[i]);
    if (i < 256 * 256) wp[i] = f2bf(pw[i]);
}

__global__ void prep_bias(const float* __restrict__ w1, const float* __restrict__ b1,
                          const float* __restrict__ w2, const float* __restrict__ b2,
                          const float* __restrict__ lsc, float* __restrict__ biasT,
                          float* __restrict__ scT) {
    int t = threadIdx.x;                         // 1 block, 128 threads
    if (t < 8) scT[t] = expf(fminf(lsc[t], logf(100.0f)));
    if (t < 127) {
        float delta = (float)(t - 63);
        float sg = (delta > 0.f) ? 1.f : ((delta < 0.f) ? -1.f : 0.f);
        float r = sg * log1pf(fabsf(delta));     // rel coord 0 is always 0
        float acc[8];
        #pragma unroll
        for (int q = 0; q < 8; ++q) acc[q] = b2[q];
        for (int m = 0; m < 384; ++m) {
            float hid = fmaxf(fmaf(r, w1[m * 2 + 1], b1[m]), 0.f);
            #pragma unroll
            for (int q = 0; q < 8; ++q) acc[q] = fmaf(hid, w2[q * 384 + m], acc[q]);
        }
        #pragma unroll
        for (int q = 0; q < 8; ++q) biasT[q * 127 + t] = acc[q];
    }
}

// ---------------- main fused kernel ----------------
// one block per window; 4 waves; head-pair loop; proj accumulated across heads.
// LDS (bytes):
//  XS  @0      bf16 [64][264]  x tile            33792
//  QG  @33792  bf16 [64][72]   q pair (raw)       9216
//  KG  @43008  bf16 [64][72]   k pair (raw)       9216
//  VT  @52224  bf16 [64][72]   v pair, transposed 9216
//  PB  @61440  bf16 [64][72]   softmaxed P        9216
//  AO  @70656  bf16 [64][56]   attn out (head)    7168
//  NSQ @77824  f32  [2][64][4] sumsq partials     2048
//  INV @79872  f32  [2][64][2] scale/norm         1024   -> total 80896

__global__ void __launch_bounds__(256, 2)
fused_win_attn(const float* __restrict__ x,
               const float* __restrict__ qkv_b,
               const float* __restrict__ proj_b,
               const short* __restrict__ wq,
               const short* __restrict__ wp,
               const float* __restrict__ biasT,
               const float* __restrict__ scT,
               float* __restrict__ out)
{
    extern __shared__ char smem[];
    short* XS = (short*)(smem);
    short* QG = (short*)(smem + 33792);
    short* KG = (short*)(smem + 43008);
    short* VT = (short*)(smem + 52224);
    short* PB = (short*)(smem + 61440);
    short* AO = (short*)(smem + 70656);
    float* NSQ = (float*)(smem + 77824);
    float* INV = (float*)(smem + 79872);

    const int tid = threadIdx.x;
    const int w  = tid >> 6;
    const int l  = tid & 63;
    const int lg = l >> 4;
    const int lc = l & 15;
    const int blk = blockIdx.x;

    // ---- stage x -> XS (bf16, padded stride 264) ----
    {
        const f32x4* xb = (const f32x4*)(x + (size_t)blk * (LTOK * CDIM));
        #pragma unroll
        for (int u = 0; u < 16; ++u) {
            int f = u * 256 + tid;          // float4 index in [0,4096)
            f32x4 v = xb[f];
            int r = f >> 6;
            int c = (f & 63) << 2;
            short4_t pk;
            pk[0] = f2bf(v[0]); pk[1] = f2bf(v[1]);
            pk[2] = f2bf(v[2]); pk[3] = f2bf(v[3]);
            *(short4_t*)(XS + r * 264 + c) = pk;
        }
    }
    __syncthreads();

    f32x4 accP[4][4];      // proj accumulators: [mt][ntl], persist across heads
    #pragma unroll
    for (int a = 0; a < 4; ++a)
        #pragma unroll
        for (int bb = 0; bb < 4; ++bb)
            accP[a][bb] = (f32x4){0.f, 0.f, 0.f, 0.f};

    const f32x4 fzero = {0.f, 0.f, 0.f, 0.f};

    for (int g = 0; g < 4; ++g) {
        // ---- qkv GEMM for heads 2g, 2g+1: wave w does 16-col strip of q,k,v ----
        #pragma unroll
        for (int s = 0; s < 3; ++s) {
            const int cb = s * 256 + g * 64 + w * 16;     // output column base
            const float bq = qkv_b[cb + lc];
            f32x4 acc[4];
            acc[0] = acc[1] = acc[2] = acc[3] = fzero;
            #pragma unroll
            for (int kt = 0; kt < 8; ++kt) {
                short8 Bf = *(const short8*)(wq + (size_t)(cb + lc) * 256 + kt * 32 + lg * 8);
                #pragma unroll
                for (int mt = 0; mt < 4; ++mt) {
                    short8 Af = *(const short8*)(XS + (mt * 16 + lc) * 264 + kt * 32 + lg * 8);
                    acc[mt] = __builtin_amdgcn_mfma_f32_16x16x32_bf16(Af, Bf, acc[mt], 0, 0, 0);
                }
            }
            if (s < 2) {
                short* dst = (s == 0) ? QG : KG;
                #pragma unroll
                for (int mt = 0; mt < 4; ++mt) {
                    #pragma unroll
                    for (int i = 0; i < 4; ++i) {
                        float v = acc[mt][i] + bq;
                        dst[(mt * 16 + lg * 4 + i) * 72 + (w * 16 + lc)] = f2bf(v);
                        float t = v * v;
                        t += __shfl_xor(t, 1);
                        t += __shfl_xor(t, 2);
                        t += __shfl_xor(t, 4);
                        t += __shfl_xor(t, 8);
                        if (lc == 0) NSQ[s * 256 + (mt * 16 + lg * 4 + i) * 4 + w] = t;
                    }
                }
            } else {
                // v: transpose-store (VT[c_local][token])
                #pragma unroll
                for (int mt = 0; mt < 4; ++mt) {
                    short4_t pk;
                    #pragma unroll
                    for (int i = 0; i < 4; ++i) pk[i] = f2bf(acc[mt][i] + bq);
                    *(short4_t*)(VT + (w * 16 + lc) * 72 + mt * 16 + lg * 4) = pk;
                }
            }
        }
        __syncthreads();
        // ---- finalize inverse norms (fold logit scale into q side) ----
        if (tid < 128) {
            int qk = tid >> 6, r = tid & 63;
            float s0 = NSQ[qk * 256 + r * 4 + 0] + NSQ[qk * 256 + r * 4 + 1];
            float s1 = NSQ[qk * 256 + r * 4 + 2] + NSQ[qk * 256 + r * 4 + 3];
            float i0 = (s0 > 1e-24f) ? rsqrtf(s0) : 1e12f;
            float i1 = (s1 > 1e-24f) ? rsqrtf(s1) : 1e12f;
            if (qk == 0) { i0 *= scT[2 * g]; i1 *= scT[2 * g + 1]; }
            INV[qk * 128 + r * 2 + 0] = i0;
            INV[qk * 128 + r * 2 + 1] = i1;
        }
        __syncthreads();

        for (int hh = 0; hh < 2; ++hh) {
            const int h = 2 * g + hh;
            // ---- QK^T: wave w = m-tile (query rows 16w..) ----
            short8 Aq = *(const short8*)(QG + (w * 16 + lc) * 72 + hh * 32 + lg * 8);
            f32x4 pacc[4];
            #pragma unroll
            for (int nt = 0; nt < 4; ++nt) {
                short8 Bk = *(const short8*)(KG + (nt * 16 + lc) * 72 + hh * 32 + lg * 8);
                pacc[nt] = __builtin_amdgcn_mfma_f32_16x16x32_bf16(Aq, Bk, fzero, 0, 0, 0);
            }
            float invq[4], invk[4];
            #pragma unroll
            for (int i = 0; i < 4; ++i) invq[i] = INV[(w * 16 + lg * 4 + i) * 2 + hh];
            #pragma unroll
            for (int nt = 0; nt < 4; ++nt) invk[nt] = INV[128 + (nt * 16 + lc) * 2 + hh];
            float p[4][4];
            #pragma unroll
            for (int i = 0; i < 4; ++i) {
                int r = w * 16 + lg * 4 + i;
                #pragma unroll
                for (int nt = 0; nt < 4; ++nt) {
                    int c = nt * 16 + lc;
                    p[i][nt] = pacc[nt][i] * invq[i] * invk[nt] + biasT[h * 127 + r - c + 63];
                }
            }
            // ---- softmax over row: 4 local vals x 16 lanes ----
            #pragma unroll
            for (int i = 0; i < 4; ++i) {
                float m = fmaxf(fmaxf(p[i][0], p[i][1]), fmaxf(p[i][2], p[i][3]));
                m = fmaxf(m, __shfl_xor(m, 1));
                m = fmaxf(m, __shfl_xor(m, 2));
                m = fmaxf(m, __shfl_xor(m, 4));
                m = fmaxf(m, __shfl_xor(m, 8));
                float ssum = 0.f;
                #pragma unroll
                for (int nt = 0; nt < 4; ++nt) { p[i][nt] = __expf(p[i][nt] - m); ssum += p[i][nt]; }
                ssum += __shfl_xor(ssum, 1);
                ssum += __shfl_xor(ssum, 2);
                ssum += __shfl_xor(ssum, 4);
                ssum += __shfl_xor(ssum, 8);
                float rinv = 1.f / ssum;
                #pragma unroll
                for (int nt = 0; nt < 4; ++nt)
                    PB[(w * 16 + lg * 4 + i) * 72 + nt * 16 + lc] = f2bf(p[i][nt] * rinv);
            }
            __syncthreads();
            // ---- P @ V ----
            f32x4 oacc[2];
            oacc[0] = oacc[1] = fzero;
            #pragma unroll
            for (int kt = 0; kt < 2; ++kt) {
                short8 Ap = *(const short8*)(PB + (w * 16 + lc) * 72 + kt * 32 + lg * 8);
                #pragma unroll
                for (int nt2 = 0; nt2 < 2; ++nt2) {
                    short8 Bv = *(const short8*)(VT + (hh * 32 + nt2 * 16 + lc) * 72 + kt * 32 + lg * 8);
                    oacc[nt2] = __builtin_amdgcn_mfma_f32_16x16x32_bf16(Ap, Bv, oacc[nt2], 0, 0, 0);
                }
            }
            #pragma unroll
            for (int nt2 = 0; nt2 < 2; ++nt2)
                #pragma unroll
                for (int i = 0; i < 4; ++i)
                    AO[(w * 16 + lg * 4 + i) * 56 + nt2 * 16 + lc] = f2bf(oacc[nt2][i]);
            __syncthreads();
            // ---- proj accumulate: wave w owns output cols 64w..64w+63, K-chunk = head h ----
            #pragma unroll
            for (int mt = 0; mt < 4; ++mt) {
                short8 Aa = *(const short8*)(AO + (mt * 16 + lc) * 56 + lg * 8);
                #pragma unroll
                for (int ntl = 0; ntl < 4; ++ntl) {
                    short8 Bp = *(const short8*)(wp + (size_t)(w * 64 + ntl * 16 + lc) * 256 + h * 32 + lg * 8);
                    accP[mt][ntl] = __builtin_amdgcn_mfma_f32_16x16x32_bf16(Aa, Bp, accP[mt][ntl], 0, 0, 0);
                }
            }
            // no barrier needed: next head's LDS writes are fenced by its own barriers
        }
    }

    // ---- epilogue: out = accP + proj_b ----
    {
        float* ob = out + (size_t)blk * (LTOK * CDIM);
        float pbv[4];
        #pragma unroll
        for (int ntl = 0; ntl < 4; ++ntl) pbv[ntl] = proj_b[w * 64 + ntl * 16 + lc];
        #pragma unroll
        for (int mt = 0; mt < 4; ++mt)
            #pragma unroll
            for (int ntl = 0; ntl < 4; ++ntl)
                #pragma unroll
                for (int i = 0; i < 4; ++i)
                    ob[(mt * 16 + lg * 4 + i) * 256 + w * 64 + ntl * 16 + lc] = accP[mt][ntl][i] + pbv[ntl];
    }
}

extern "C" void kernel_launch(void* const* d_in, const int* in_sizes, int n_in,
                              void* d_out, int out_size, void* d_ws, size_t ws_size,
                              hipStream_t stream) {
    const float* x     = (const float*)d_in[0];
    const float* qkvw  = (const float*)d_in[1];
    const float* qkvb  = (const float*)d_in[2];
    const float* projw = (const float*)d_in[3];
    const float* projb = (const float*)d_in[4];
    const float* lsc   = (const float*)d_in[5];
    const float* w1    = (const float*)d_in[6];
    const float* b1    = (const float*)d_in[7];
    const float* w2    = (const float*)d_in[8];
    const float* b2    = (const float*)d_in[9];
    float* out = (float*)d_out;

    // workspace layout
    short* wq    = (short*)d_ws;                          // 393216 B
    short* wp    = (short*)((char*)d_ws + 393216);        // 131072 B
    float* biasT = (float*)((char*)d_ws + 524288);        // 4096 B
    float* scT   = (float*)((char*)d_ws + 528384);        // 32 B

    const int nwin = in_sizes[0] / (LTOK * CDIM);         // 4096
    const int lds_bytes = 80896;

    hipFuncSetAttribute((const void*)fused_win_attn,
                        hipFuncAttributeMaxDynamicSharedMemorySize, lds_bytes);

    prep_weights<<<768, 256, 0, stream>>>(qkvw, projw, wq, wp);
    prep_bias<<<1, 128, 0, stream>>>(w1, b1, w2, b2, lsc, biasT, scT);
    fused_win_attn<<<nwin, 256, lds_bytes, stream>>>(x, qkvb, projb, wq, wp, biasT, scT, out);
}